// Round 1
// baseline (28.509 us; speedup 1.0000x reference)
//
#include <hip/hip_runtime.h>

// Problem constants (match the reference file).
#define IN_F   4096
#define OUT_F  4094   // IN_FEATURES - 2
#define BATCH_ 4096
#define WCOLS  3      // min(3, OUT_F)

// ---------------------------------------------------------------------------
// Kernel 1: zero-fill the whole output buffer with vectorized float4 stores.
// total floats = 4096*4094 = 16,769,024 -> 4,192,256 float4 (exactly divisible).
// ---------------------------------------------------------------------------
__global__ __launch_bounds__(256) void zero_fill_kernel(float4* __restrict__ out,
                                                        long n4) {
    long i = (long)blockIdx.x * blockDim.x + threadIdx.x;
    long stride = (long)gridDim.x * blockDim.x;
    const float4 z = make_float4(0.f, 0.f, 0.f, 0.f);
    for (; i < n4; i += stride) {
        out[i] = z;
    }
}

// ---------------------------------------------------------------------------
// Kernel 2: skinny GEMM — out[b, j] = dot(input[b,:], weight[j,:]) + N*bias[j]
// for j in 0..2. One 256-thread block per row b. float4 loads throughout.
// Weight rows 0..2 (48 KB) are re-read by every block -> L2-resident.
// ---------------------------------------------------------------------------
__global__ __launch_bounds__(256) void skinny_dot_kernel(const float* __restrict__ in,
                                                         const float* __restrict__ w,
                                                         const float* __restrict__ bias,
                                                         float* __restrict__ out) {
    const int b   = blockIdx.x;
    const int tid = threadIdx.x;

    const float4* __restrict__ row = (const float4*)(in + (long)b * IN_F);
    const float4* __restrict__ w0  = (const float4*)(w);
    const float4* __restrict__ w1  = (const float4*)(w + IN_F);
    const float4* __restrict__ w2  = (const float4*)(w + 2 * IN_F);

    float s0 = 0.f, s1 = 0.f, s2 = 0.f;

    // IN_F/4 = 1024 float4 per row; 256 threads -> 4 iterations each.
    #pragma unroll 4
    for (int i = tid; i < IN_F / 4; i += 256) {
        float4 x = row[i];
        float4 a = w0[i];
        float4 c = w1[i];
        float4 d = w2[i];
        s0 = fmaf(x.x, a.x, fmaf(x.y, a.y, fmaf(x.z, a.z, fmaf(x.w, a.w, s0))));
        s1 = fmaf(x.x, c.x, fmaf(x.y, c.y, fmaf(x.z, c.z, fmaf(x.w, c.w, s1))));
        s2 = fmaf(x.x, d.x, fmaf(x.y, d.y, fmaf(x.z, d.z, fmaf(x.w, d.w, s2))));
    }

    // Wave-level reduction (wave = 64 lanes on gfx950).
    #pragma unroll
    for (int off = 32; off > 0; off >>= 1) {
        s0 += __shfl_down(s0, off);
        s1 += __shfl_down(s1, off);
        s2 += __shfl_down(s2, off);
    }

    __shared__ float red[4][WCOLS];
    const int wave = tid >> 6;
    const int lane = tid & 63;
    if (lane == 0) {
        red[wave][0] = s0;
        red[wave][1] = s1;
        red[wave][2] = s2;
    }
    __syncthreads();

    if (tid < WCOLS) {
        float t = red[0][tid] + red[1][tid] + red[2][tid] + red[3][tid];
        out[(long)b * OUT_F + tid] = t + (float)IN_F * bias[tid];
    }
}

extern "C" void kernel_launch(void* const* d_in, const int* in_sizes, int n_in,
                              void* d_out, int out_size, void* d_ws, size_t ws_size,
                              hipStream_t stream) {
    const float* in   = (const float*)d_in[0];   // (4096, 4096) fp32
    const float* w    = (const float*)d_in[1];   // (4094, 4096) fp32
    const float* bias = (const float*)d_in[2];   // (4094,) fp32
    float* out = (float*)d_out;                  // (4096, 4094) fp32

    // 1) zero-fill entire output
    const long n4 = (long)BATCH_ * OUT_F / 4;    // divisible: 16,769,024 / 4
    zero_fill_kernel<<<2048, 256, 0, stream>>>((float4*)out, n4);

    // 2) compute the 3 live columns (overwrites the zeros at cols 0..2)
    skinny_dot_kernel<<<BATCH_, 256, 0, stream>>>(in, w, bias, out);
}